// Round 11
// baseline (9866.846 us; speedup 1.0000x reference)
//
#include <hip/hip_runtime.h>

#define BB 256
#define TT 256
#define II 256
#define HH 1024
#define LL 128
#define K1 1280   // HH + II
#define GN 3072   // 3*HH
#define BBHH (BB * HH)

#define RP2 97    // red row stride (floats)
#define GP2 33    // gxn row stride
#define PP 20     // pred row stride

typedef short s8v    __attribute__((ext_vector_type(8)));
typedef float f32x4  __attribute__((ext_vector_type(4)));
typedef float f4v    __attribute__((ext_vector_type(4)));
typedef unsigned long long u64;
typedef unsigned short us;

__device__ __forceinline__ us f2bf(float f) {
    unsigned u = __float_as_uint(f);
    u += 0x7fffu + ((u >> 16) & 1u);
    return (us)(u >> 16);
}
__device__ __forceinline__ float bf2f(us h) {
    return __uint_as_float(((unsigned)h) << 16);
}
__device__ __forceinline__ float sigm(float x) { return 1.0f / (1.0f + __expf(-x)); }

__device__ __forceinline__ s8v cvt8(const float* __restrict__ p) {
    const f4v lo = *(const f4v*)p;
    const f4v hi = *(const f4v*)(p + 4);
    s8v r;
    r[0] = (short)f2bf(lo[0]); r[1] = (short)f2bf(lo[1]);
    r[2] = (short)f2bf(lo[2]); r[3] = (short)f2bf(lo[3]);
    r[4] = (short)f2bf(hi[0]); r[5] = (short)f2bf(hi[1]);
    r[6] = (short)f2bf(hi[2]); r[7] = (short)f2bf(hi[3]);
    return r;
}

// sc1 (coherence-point) 16B load, for the 3-slot fallback
__device__ __forceinline__ s8v hload16a(const us* p) {
    union { u64 q[2]; s8v v; } u;
    u.q[0] = __hip_atomic_load((const u64*)p, __ATOMIC_RELAXED, __HIP_MEMORY_SCOPE_AGENT);
    u.q[1] = __hip_atomic_load((const u64*)p + 1, __ATOMIC_RELAXED, __HIP_MEMORY_SCOPE_AGENT);
    return u.v;
}
// FRESH: slot-per-step -> plain loads of never-stale addresses (round-8-proven);
// line fills into the consumer XCD's L2 and is shared by sibling WGs there.
template<int FRESH> __device__ __forceinline__ s8v ld16h(const us* p) {
    if constexpr (FRESH) return *(const s8v*)p;
    else return hload16a(p);
}
template<int FRESH> __device__ __forceinline__ u64 ld8h(const us* p) {
    if constexpr (FRESH) return *(const u64*)p;
    else return __hip_atomic_load((const u64*)p, __ATOMIC_RELAXED, __HIP_MEMORY_SCOPE_AGENT);
}
// h stores: ALWAYS sc1 (consumers are cross-XCD under nt-major mapping)
__device__ __forceinline__ void h_store8(us* p, u64 v) {
    __hip_atomic_store((u64*)p, v, __ATOMIC_RELAXED, __HIP_MEMORY_SCOPE_AGENT);
}
// flags: agent scope (proven rounds 5/6/8/10)
__device__ __forceinline__ void flag_store(unsigned* p, unsigned v) {
    __hip_atomic_store(p, v, __ATOMIC_RELAXED, __HIP_MEMORY_SCOPE_AGENT);
}
__device__ __forceinline__ unsigned flag_probe(unsigned* p) {
    return __hip_atomic_load(p, __ATOMIC_RELAXED, __HIP_MEMORY_SCOPE_AGENT);
}
// wave-0 group barrier: all 32 member flags >= t
__device__ __forceinline__ void group_wait(unsigned* gf, int lane, unsigned t) {
    if (t == 0) return;
    int guard = 0;
    for (;;) {
        unsigned v = t;
        if (lane < 32) v = flag_probe(gf + lane);
        if (__ballot(v >= t) == ~0ull) break;
        __builtin_amdgcn_s_sleep(1);
        if (++guard > (1 << 18)) break;   // safety valve
    }
    asm volatile("" ::: "memory");
}

// ---- prep: permuted gate weights, 96-row blocks per WG (unchanged) ----
__global__ void k_prep_w(const float* __restrict__ Whh, const float* __restrict__ Wih,
                         us* __restrict__ Wperm) {
    int o = blockIdx.x;                 // 3072
    int ntt = o / 96, q = o - ntt * 96;
    int gate = q >> 5, jj = q & 31;
    int src = gate * HH + ntt * 32 + jj;
    const float* sh = Whh + (size_t)src * HH;
    const float* si = Wih + (size_t)src * II;
    us* dst = Wperm + (size_t)o * K1;
    for (int k = threadIdx.x; k < K1; k += 256)
        dst[k] = f2bf(k < HH ? sh[k] : si[k - HH]);
}

__global__ void k_prep_misc(const float* __restrict__ bih, const float* __restrict__ bhh,
                            const float* __restrict__ Wout,
                            float* __restrict__ bihp, float* __restrict__ bhhp,
                            us* __restrict__ Woutb) {
    int idx = blockIdx.x * 256 + threadIdx.x;
    if (idx < GN) {
        int ntt = idx / 96, q = idx - ntt * 96;
        int gate = q >> 5, jj = q & 31;
        int src = gate * HH + ntt * 32 + jj;
        bihp[idx] = bih[src];
        bhhp[idx] = bhh[src];
    }
    for (size_t i = (size_t)blockIdx.x * 256 + threadIdx.x; i < (size_t)II * HH;
         i += (size_t)gridDim.x * 256)
        Woutb[i] = f2bf(Wout[i]);
}

__global__ void k_h0(const float* __restrict__ z, const float* __restrict__ Wz,
                     const float* __restrict__ bz, us* __restrict__ hbuf) {
    int b = blockIdx.x;
    int j0 = threadIdx.x * 4;
    const f4v* zr = (const f4v*)(z + (size_t)b * LL);
    u64 packed = 0;
#pragma unroll
    for (int jj = 0; jj < 4; ++jj) {
        int j = j0 + jj;
        const f4v* wr = (const f4v*)(Wz + (size_t)j * LL);
        float s = bz[j];
#pragma unroll
        for (int i = 0; i < LL / 4; ++i) {
            f4v a = zr[i], w = wr[i];
            s += a[0] * w[0] + a[1] * w[1] + a[2] * w[2] + a[3] * w[3];
        }
        packed |= (u64)f2bf(tanhf(s)) << (16 * jj);
    }
    *(u64*)(hbuf + (size_t)b * HH + j0) = packed;   // kernel-end flush -> visible
}

// output projection: one 16x16 tile, K=1024 split across 4 waves
template<int FRESH>
__device__ __forceinline__ void proj_tile(
    const us* hb, const us* __restrict__ Woutb,
    float* __restrict__ out, float (*pred)[16 * PP],
    int brow, int it, int wave, int lane, int lr, int lk, int tp, float boutv) {
    f32x4 oa = {0.f, 0.f, 0.f, 0.f};
    const us* ap = hb + (size_t)(brow + lr) * HH + (wave << 8) + lk;
    const us* wp = Woutb + (size_t)(it * 16 + lr) * HH + (wave << 8) + lk;
#pragma unroll
    for (int ks = 0; ks < 8; ++ks) {
        s8v a = ld16h<FRESH>(ap + ks * 32);
        s8v w = *(const s8v*)(wp + ks * 32);
        oa = __builtin_amdgcn_mfma_f32_16x16x32_bf16(a, w, oa, 0, 0, 0);
    }
    if (wave >= 1) {
#pragma unroll
        for (int r = 0; r < 4; ++r)
            pred[wave - 1][(((lane >> 4) << 2) + r) * PP + lr] = oa[r];
    }
    __syncthreads();
    if (wave == 0) {
#pragma unroll
        for (int r = 0; r < 4; ++r) {
            int rw = ((lane >> 4) << 2) + r;
            int idx = rw * PP + lr;
            float v = oa[r] + pred[0][idx] + pred[1][idx] + pred[2][idx] + boutv;
            out[(size_t)(brow + rw) * (TT * II) + (size_t)tp * II + it * 16 + lr] = sigm(v);
        }
    }
    __syncthreads();
}

// ---- main loop, nt-major XCD mapping ----
// bid = x + 8*q + 32*g  (x = nt>>2 selects XCD; q = nt&3; g = batch-group)
// -> W slice nt is read ONLY on XCD x (8 WGs share it): W per XCD = 983 KB, L2-resident.
// -> h handoff is cross-XCD: sc1 stores + fresh plain loads + agent flags.
template<int FRESH>
__device__ void run11(const float* __restrict__ tgt, const us* __restrict__ Wperm,
                      const float* __restrict__ bihp, const float* __restrict__ bhhp,
                      us* hbuf, const us* __restrict__ Woutb,
                      const float* __restrict__ bout, float* __restrict__ out,
                      unsigned* flags,
                      float (*red)[32 * RP2], float* gxn, float (*pred)[16 * PP]) {
    const int tid = threadIdx.x;
    const int wave = tid >> 6, lane = tid & 63;
    const int lr = lane & 15;
    const int lk = (lane >> 4) << 3;
    const int hi4 = ((lane >> 4) << 2);
    const int bid = blockIdx.x;
    const int x = bid & 7, q = (bid >> 3) & 3, g = bid >> 5;
    const int nt = x * 4 + q;
    const int bt = nt >> 4, it = nt & 15;
    const int brow = g * 32 + bt * 16;
    const float boutv = bout[it * 16 + lr];

    // epilogue ownership: batch eb (0..31), 4 j starting at jq*4
    const int eb = tid & 31, jq = tid >> 5;
    const int ob = nt * 96;
    float bir[4], biz[4], bixn[4], bihn[4];
#pragma unroll
    for (int jj = 0; jj < 4; ++jj) {
        int lj = jq * 4 + jj;
        bir[jj]  = bihp[ob + lj] + bhhp[ob + lj];
        biz[jj]  = bihp[ob + 32 + lj] + bhhp[ob + 32 + lj];
        bixn[jj] = bihp[ob + 64 + lj];
        bihn[jj] = bhhp[ob + 64 + lj];
    }

    unsigned* gflags = flags + (g << 6);   // 32 words used, 64-stride padding

    for (int t = 0; t < TT; ++t) {
        const us* hcur = hbuf + (size_t)(FRESH ? t : (t % 3)) * BBHH;
        us* hnxt = hbuf + (size_t)(FRESH ? (t + 1) : ((t + 1) % 3)) * BBHH;

        f32x4 acc[12];   // [mi*6+ni]
#pragma unroll
        for (int i = 0; i < 12; ++i) acc[i] = (f32x4){0.f, 0.f, 0.f, 0.f};
        f32x4 accx[4];   // [mi*2 + (ni-4)] : x-part of n-gate
#pragma unroll
        for (int i = 0; i < 4; ++i) accx[i] = (f32x4){0.f, 0.f, 0.f, 0.f};

        // wave 3: x-part GEMM BEFORE the barrier (constant X)
        if (wave == 3) {
#pragma unroll
            for (int ks = 0; ks < 8; ++ks) {
                const int k0 = ks * 32 + lk;
                s8v xa[2], w[6];
#pragma unroll
                for (int mi = 0; mi < 2; ++mi)
                    xa[mi] = cvt8(tgt + ((size_t)(g * 32 + mi * 16 + lr) * TT + t) * II + k0);
#pragma unroll
                for (int ni = 0; ni < 6; ++ni)
                    w[ni] = *(const s8v*)(Wperm + (size_t)(ob + ni * 16 + lr) * K1 + HH + k0);
#pragma unroll
                for (int mi = 0; mi < 2; ++mi) {
#pragma unroll
                    for (int ni = 0; ni < 4; ++ni)
                        acc[mi * 6 + ni] = __builtin_amdgcn_mfma_f32_16x16x32_bf16(
                            xa[mi], w[ni], acc[mi * 6 + ni], 0, 0, 0);
                    accx[mi * 2 + 0] = __builtin_amdgcn_mfma_f32_16x16x32_bf16(
                        xa[mi], w[4], accx[mi * 2 + 0], 0, 0, 0);
                    accx[mi * 2 + 1] = __builtin_amdgcn_mfma_f32_16x16x32_bf16(
                        xa[mi], w[5], accx[mi * 2 + 1], 0, 0, 0);
                }
            }
        }

        // barrier: all 32 group members have published h_t
        if (wave == 0) group_wait(gflags, lane, (unsigned)t);
        __syncthreads();

        // h-part GEMM (W from L2; h plain loads pull sc1 data from coherence point)
        if (wave < 3) {
#pragma unroll
            for (int ci = 0; ci < 10; ++ci) {
                const int k0 = wave * 320 + ci * 32 + lk;
                s8v a[2], w[6];
#pragma unroll
                for (int mi = 0; mi < 2; ++mi)
                    a[mi] = ld16h<FRESH>(hcur + (size_t)(g * 32 + mi * 16 + lr) * HH + k0);
#pragma unroll
                for (int ni = 0; ni < 6; ++ni)
                    w[ni] = *(const s8v*)(Wperm + (size_t)(ob + ni * 16 + lr) * K1 + k0);
#pragma unroll
                for (int mi = 0; mi < 2; ++mi)
#pragma unroll
                    for (int ni = 0; ni < 6; ++ni)
                        acc[mi * 6 + ni] = __builtin_amdgcn_mfma_f32_16x16x32_bf16(
                            a[mi], w[ni], acc[mi * 6 + ni], 0, 0, 0);
            }
        } else {
#pragma unroll
            for (int ks = 0; ks < 2; ++ks) {
                const int k0 = 960 + ks * 32 + lk;
                s8v a[2], w[6];
#pragma unroll
                for (int mi = 0; mi < 2; ++mi)
                    a[mi] = ld16h<FRESH>(hcur + (size_t)(g * 32 + mi * 16 + lr) * HH + k0);
#pragma unroll
                for (int ni = 0; ni < 6; ++ni)
                    w[ni] = *(const s8v*)(Wperm + (size_t)(ob + ni * 16 + lr) * K1 + k0);
#pragma unroll
                for (int mi = 0; mi < 2; ++mi)
#pragma unroll
                    for (int ni = 0; ni < 6; ++ni)
                        acc[mi * 6 + ni] = __builtin_amdgcn_mfma_f32_16x16x32_bf16(
                            a[mi], w[ni], acc[mi * 6 + ni], 0, 0, 0);
            }
#pragma unroll
            for (int mi = 0; mi < 2; ++mi)
#pragma unroll
                for (int n2 = 0; n2 < 2; ++n2)
#pragma unroll
                    for (int r = 0; r < 4; ++r)
                        gxn[(mi * 16 + hi4 + r) * GP2 + n2 * 16 + lr] = accx[mi * 2 + n2][r];
        }

        // all 4 waves write partials; epilogue sums the 4 sets
        {
            float* s = &red[wave][0];
#pragma unroll
            for (int mi = 0; mi < 2; ++mi)
#pragma unroll
                for (int ni = 0; ni < 6; ++ni)
#pragma unroll
                    for (int r = 0; r < 4; ++r)
                        s[(mi * 16 + hi4 + r) * RP2 + ni * 16 + lr] = acc[mi * 6 + ni][r];
        }
        __syncthreads();

        // gate epilogue: thread (eb, jq*4..+3) -> one 8B sc1 h store
        {
            const int bg = g * 32 + eb;
            const int jbase = nt * 32 + jq * 4;
            u64 hold8 = ld8h<FRESH>(hcur + (size_t)bg * HH + jbase);
            u64 packed = 0;
#pragma unroll
            for (int jj = 0; jj < 4; ++jj) {
                int lj = jq * 4 + jj;
                float ghr = red[0][eb * RP2 + lj] + red[1][eb * RP2 + lj] +
                            red[2][eb * RP2 + lj] + red[3][eb * RP2 + lj];
                float ghz = red[0][eb * RP2 + 32 + lj] + red[1][eb * RP2 + 32 + lj] +
                            red[2][eb * RP2 + 32 + lj] + red[3][eb * RP2 + 32 + lj];
                float ghn = red[0][eb * RP2 + 64 + lj] + red[1][eb * RP2 + 64 + lj] +
                            red[2][eb * RP2 + 64 + lj] + red[3][eb * RP2 + 64 + lj];
                float gx  = gxn[eb * GP2 + lj];
                float r   = sigm(ghr + bir[jj]);
                float zg  = sigm(ghz + biz[jj]);
                float n   = tanhf(gx + bixn[jj] + r * (ghn + bihn[jj]));
                float ho  = bf2f((us)(hold8 >> (16 * jj)));
                packed |= (u64)f2bf((1.f - zg) * n + zg * ho) << (16 * jj);
            }
            h_store8(hnxt + (size_t)bg * HH + jbase, packed);
        }

        // arrive: drain sc1 h stores to coherence point, then signal
        asm volatile("s_waitcnt vmcnt(0)" ::: "memory");
        __syncthreads();
        if (tid == 0) flag_store(gflags + nt, (unsigned)(t + 1));

        // project y_{t-1} from h_t while peers' flags propagate
        if (t > 0)
            proj_tile<FRESH>(hcur, Woutb, out, pred, brow, it, wave, lane, lr, lk,
                             t - 1, boutv);
    }

    // tail: y_{T-1} from h_T
    if (wave == 0) group_wait(gflags, lane, (unsigned)TT);
    __syncthreads();
    proj_tile<FRESH>(hbuf + (size_t)(FRESH ? TT : (TT % 3)) * BBHH,
                     Woutb, out, pred, brow, it, wave, lane, lr, lk, TT - 1, boutv);
}

__global__ __launch_bounds__(256, 1) void dec11(
    const float* __restrict__ tgt, const us* __restrict__ Wperm,
    const float* __restrict__ bihp, const float* __restrict__ bhhp,
    us* hbuf, const us* __restrict__ Woutb,
    const float* __restrict__ bout, float* __restrict__ out,
    unsigned* flags, int fresh) {
    __shared__ float red[4][32 * RP2];
    __shared__ float gxn[32 * GP2];
    __shared__ float pred[3][16 * PP];
    if (fresh)
        run11<1>(tgt, Wperm, bihp, bhhp, hbuf, Woutb, bout, out, flags, red, gxn, pred);
    else
        run11<0>(tgt, Wperm, bihp, bhhp, hbuf, Woutb, bout, out, flags, red, gxn, pred);
}

// ---- diagnostic: pure agent-flag barrier, 4096 iterations, isolated buffer ----
// Appears in top-5 iff one 32-WG barrier costs >= ~1.6 us; then dur/4096 = cost.
__global__ __launch_bounds__(256, 1) void abl_flag4096(unsigned* f2) {
    const int tid = threadIdx.x, bid = blockIdx.x;
    const int g = bid >> 5;
    const int nt = (bid & 7) * 4 + ((bid >> 3) & 3);
    const int wave = tid >> 6, lane = tid & 63;
    unsigned* gf = f2 + (g << 6);
    for (int t = 0; t < 4096; ++t) {
        __syncthreads();
        if (tid == 0) flag_store(gf + nt, (unsigned)(t + 1));
        if (wave == 0) group_wait(gf, lane, (unsigned)(t + 1));
        __syncthreads();
    }
}

extern "C" void kernel_launch(void* const* d_in, const int* in_sizes, int n_in,
                              void* d_out, int out_size, void* d_ws, size_t ws_size,
                              hipStream_t stream) {
    const float* z    = (const float*)d_in[0];
    const float* tgt  = (const float*)d_in[2];
    const float* Wz2h = (const float*)d_in[3];
    const float* bz2h = (const float*)d_in[4];
    const float* Wih  = (const float*)d_in[5];
    const float* Whh  = (const float*)d_in[6];
    const float* bih  = (const float*)d_in[7];
    const float* bhh  = (const float*)d_in[8];
    const float* Wout = (const float*)d_in[9];
    const float* bout = (const float*)d_in[10];
    float* out = (float*)d_out;

    char* ws = (char*)d_ws;
    us* Wperm        = (us*)ws;                          // 7,864,320
    float* bihp      = (float*)(ws + 7864320);           //    12,288
    float* bhhp      = (float*)(ws + 7876608);           //    12,288
    us* Woutb        = (us*)(ws + 7888896);              //   524,288
    unsigned* flags  = (unsigned*)(ws + 8413184);        //     2,048 (8 grp x 64 words)
    unsigned* flags2 = (unsigned*)(ws + 8415232);        //     2,048 (ablation, isolated)
    us* hbuf         = (us*)(ws + 8417280);              // 257 or 3 slots x 524,288

    const size_t slotB = (size_t)BBHH * 2;
    const size_t need_big = 8417280ull + 257ull * slotB;
    const int fresh = (ws_size >= need_big) ? 1 : 0;

    hipMemsetAsync((void*)flags, 0, 4096, stream);
    hipLaunchKernelGGL(k_prep_w, dim3(GN), dim3(256), 0, stream, Whh, Wih, Wperm);
    hipLaunchKernelGGL(k_prep_misc, dim3(1024), dim3(256), 0, stream, bih, bhh, Wout,
                       bihp, bhhp, Woutb);
    hipLaunchKernelGGL(k_h0, dim3(BB), dim3(256), 0, stream, z, Wz2h, bz2h, hbuf);
    hipLaunchKernelGGL(dec11, dim3(256), dim3(256), 0, stream,
                       tgt, Wperm, bihp, bhhp, hbuf, Woutb, bout, out, flags, fresh);
    // diagnostic after real consumers; isolated flag buffer
    hipLaunchKernelGGL(abl_flag4096, dim3(256), dim3(256), 0, stream, flags2);
}